// Round 1
// baseline (438.239 us; speedup 1.0000x reference)
//
#include <hip/hip_runtime.h>

typedef unsigned int uint32;
typedef uint32 v4u __attribute__((ext_vector_type(4)));

#define Bb 32
#define Pp 196
#define Dd 512
#define Hh 8
#define Uu 4
#define Cc 500

// Outputs (float32), concatenated flat:
// out0: known_prompts   (B*C, 11, D) -> 90,112,000 elems
// out1: unknown_prompts (B, 7, D)    -> 114,688 elems @ 90,112,000
// out2: semantic_tokens (B, H, D)    -> 131,072 elems @ 90,226,688
#define OUT1_ELEM_OFF 90112000
#define OUT2_ELEM_OFF 90226688

#define NPC 16   // p-chunks for pooling partials

// ws layout (float element offsets; all 16B-aligned)
#define WS_SC   0          // scores (B,H,P)          = 50,176 floats
#define WS_PART 51200      // partials (B,NPC,H,D)    = 2,097,152 floats
#define WS_DOM  2148352    // projected_domain (B,D)  = 16,384 floats
#define WS_SEM  2164736    // projected_sem (B,H,D)   = 131,072 floats

__device__ __forceinline__ float dot4(float4 a, float4 b, float acc) {
    acc = fmaf(a.x, b.x, acc);
    acc = fmaf(a.y, b.y, acc);
    acc = fmaf(a.z, b.z, acc);
    acc = fmaf(a.w, b.w, acc);
    return acc;
}

// ---------------- K1: scores[b,h,p] = patch[b,p,:].query[h,:] ----------------
// grid = B*49 = 1568, block = 256 (4 waves, one p per wave)
__global__ __launch_bounds__(256)
void k_scores(const float* __restrict__ patch, const float* __restrict__ query,
              float* __restrict__ sc) {
    __shared__ float s_q[Hh * Dd];   // 16 KB
    const int b = blockIdx.x / 49;
    const int p0 = (blockIdx.x % 49) * 4;
    const int tid = threadIdx.x;
    for (int j = tid; j < Hh * Dd / 4; j += 256)
        ((float4*)s_q)[j] = ((const float4*)query)[j];
    __syncthreads();

    const int wave = tid >> 6, lane = tid & 63;
    const int p = p0 + wave;
    const float* pr = patch + ((size_t)b * Pp + p) * Dd + lane * 8;
    const float4 v0 = *(const float4*)pr;
    const float4 v1 = *(const float4*)(pr + 4);

    float out = 0.f;
#pragma unroll
    for (int h = 0; h < 8; ++h) {
        const float4 q0 = *(const float4*)&s_q[h * Dd + lane * 8];
        const float4 q1 = *(const float4*)&s_q[h * Dd + lane * 8 + 4];
        float a = dot4(v0, q0, 0.f);
        a = dot4(v1, q1, a);
#pragma unroll
        for (int m = 32; m >= 1; m >>= 1) a += __shfl_xor(a, m, 64);
        if (lane == h) out = a;
    }
    if (lane < 8) sc[((size_t)b * Hh + lane) * Pp + p] = out;
}

// ---------------- K2: softmax (in-block, redundant per chunk) + pooling partials ----------------
// grid = B*NPC = 512 (b, p-chunk of 13), block = 256
__global__ __launch_bounds__(256)
void k_pool_part(const float* __restrict__ patch, const float* __restrict__ sc,
                 float* __restrict__ part) {
    __shared__ float s_w[Hh * Pp];   // scores -> weights, 6.3 KB
    const int b = blockIdx.x >> 4;
    const int pc = blockIdx.x & 15;
    const int tid = threadIdx.x;

    for (int j = tid; j < Hh * Pp; j += 256) s_w[j] = sc[(size_t)b * Hh * Pp + j];
    __syncthreads();

    // softmax over p for h = tid>>5, 32-lane group
    {
        const int h = tid >> 5, gl = tid & 31;
        float m = -1e30f;
        for (int p = gl; p < Pp; p += 32) m = fmaxf(m, s_w[h * Pp + p]);
#pragma unroll
        for (int mm = 16; mm >= 1; mm >>= 1) m = fmaxf(m, __shfl_xor(m, mm, 64));
        float s = 0.f;
        for (int p = gl; p < Pp; p += 32) s += __expf(s_w[h * Pp + p] - m);
#pragma unroll
        for (int mm = 16; mm >= 1; mm >>= 1) s += __shfl_xor(s, mm, 64);
        const float inv = 1.f / s;
        for (int p = gl; p < Pp; p += 32)
            s_w[h * Pp + p] = __expf(s_w[h * Pp + p] - m) * inv;  // disjoint p per thread
    }
    __syncthreads();

    // partial st over this p-chunk: thread = (hq = tid>>7, f = tid&127 float4 of D)
    const int f = tid & 127;
    const int hq = tid >> 7;
    const int pstart = pc * 13;
    const int pend = (pstart + 13 < Pp) ? pstart + 13 : Pp;
    float4 a0 = {0, 0, 0, 0}, a1 = a0, a2 = a0, a3 = a0;
    const float4* pb4 = (const float4*)(patch + (size_t)b * Pp * Dd);
    for (int p = pstart; p < pend; ++p) {
        const float4 pv = pb4[p * 128 + f];
        const float w0 = s_w[(hq * 4 + 0) * Pp + p];
        const float w1 = s_w[(hq * 4 + 1) * Pp + p];
        const float w2 = s_w[(hq * 4 + 2) * Pp + p];
        const float w3 = s_w[(hq * 4 + 3) * Pp + p];
        a0.x = fmaf(w0, pv.x, a0.x); a0.y = fmaf(w0, pv.y, a0.y);
        a0.z = fmaf(w0, pv.z, a0.z); a0.w = fmaf(w0, pv.w, a0.w);
        a1.x = fmaf(w1, pv.x, a1.x); a1.y = fmaf(w1, pv.y, a1.y);
        a1.z = fmaf(w1, pv.z, a1.z); a1.w = fmaf(w1, pv.w, a1.w);
        a2.x = fmaf(w2, pv.x, a2.x); a2.y = fmaf(w2, pv.y, a2.y);
        a2.z = fmaf(w2, pv.z, a2.z); a2.w = fmaf(w2, pv.w, a2.w);
        a3.x = fmaf(w3, pv.x, a3.x); a3.y = fmaf(w3, pv.y, a3.y);
        a3.z = fmaf(w3, pv.z, a3.z); a3.w = fmaf(w3, pv.w, a3.w);
    }
    float4* po = (float4*)part + ((size_t)b * NPC + pc) * 1024;   // 1024 float4 = H*D/4
    po[(hq * 4 + 0) * 128 + f] = a0;
    po[(hq * 4 + 1) * 128 + f] = a1;
    po[(hq * 4 + 2) * 128 + f] = a2;
    po[(hq * 4 + 3) * 128 + f] = a3;
}

// ---------------- K3: combine partials -> semantic_tokens (out2) ----------------
// grid = 128, block = 256; one float4 per thread over B*H*D/4 = 32768
__global__ __launch_bounds__(256)
void k_combine(const float* __restrict__ part, float* __restrict__ st) {
    const int idx = blockIdx.x * 256 + threadIdx.x;
    const int b = idx >> 10;
    const int r = idx & 1023;
    const float4* p4 = (const float4*)part;
    float4 a = {0, 0, 0, 0};
#pragma unroll
    for (int pc = 0; pc < NPC; ++pc) {
        const float4 v = p4[((size_t)b * NPC + pc) * 1024 + r];
        a.x += v.x; a.y += v.y; a.z += v.z; a.w += v.w;
    }
    ((float4*)st)[idx] = a;
}

// ---------------- K4: dom + sem projections (LDS-tiled, vector ds_read) ----------------
// grid = 192: blk<128 -> sem (h = blk>>4, e-tile of 32); blk>=128 -> dom (64 blocks)
// PJS=516: rows 16B-aligned (516*4 % 16 == 0); thread reads rows {pe,pe+16}/{pb,pb+16}
// so ds_read_b128 row-starts spread over all 8 bank-quads (<=2-way, free).
#define PJS 516
__global__ __launch_bounds__(256)
void k_proj(const float* __restrict__ gf, const float* __restrict__ domW,
            const float* __restrict__ domb, const float* __restrict__ semW,
            const float* __restrict__ semb, const float* __restrict__ st,
            float* __restrict__ dom_ws, float* __restrict__ sem_ws) {
    __shared__ float s_w[32 * PJS];    // 66,048 B
    __shared__ float s_st[32 * PJS];   // 66,048 B
    const int blk = blockIdx.x;
    const int tid = threadIdx.x;
    if (blk < 128) {
        const int h = blk >> 4;
        const int e0 = (blk & 15) * 32;
        for (int g = tid; g < 32 * 128; g += 256) {
            const int r = g >> 7, c4 = g & 127;
            const float4 w = ((const float4*)semW)[((size_t)(h * Dd + e0 + r)) * 128 + c4];
            *(float4*)&s_w[r * PJS + c4 * 4] = w;
            const float4 s = ((const float4*)st)[((size_t)(r * Hh + h)) * 128 + c4];
            *(float4*)&s_st[r * PJS + c4 * 4] = s;
        }
        __syncthreads();
        const int pe = tid & 15;       // e = e0 + pe, e0 + pe + 16
        const int pb = tid >> 4;       // b = pb, pb + 16
        const float* w0r = &s_w[pe * PJS];
        const float* w1r = &s_w[(pe + 16) * PJS];
        const float* s0r = &s_st[pb * PJS];
        const float* s1r = &s_st[(pb + 16) * PJS];
        float a00 = 0.f, a01 = 0.f, a10 = 0.f, a11 = 0.f;
#pragma unroll 4
        for (int d = 0; d < Dd; d += 4) {
            const float4 w0 = *(const float4*)&w0r[d];
            const float4 w1 = *(const float4*)&w1r[d];
            const float4 s0 = *(const float4*)&s0r[d];
            const float4 s1 = *(const float4*)&s1r[d];
            a00 = dot4(s0, w0, a00);
            a01 = dot4(s0, w1, a01);
            a10 = dot4(s1, w0, a10);
            a11 = dot4(s1, w1, a11);
        }
        const int e_ = e0 + pe;
        const float b0 = semb[h * Dd + e_], b1 = semb[h * Dd + e_ + 16];
        sem_ws[((size_t)pb * Hh + h) * Dd + e_]             = a00 + b0;
        sem_ws[((size_t)pb * Hh + h) * Dd + e_ + 16]        = a01 + b1;
        sem_ws[((size_t)(pb + 16) * Hh + h) * Dd + e_]      = a10 + b0;
        sem_ws[((size_t)(pb + 16) * Hh + h) * Dd + e_ + 16] = a11 + b1;
    } else {
        const int tg = (blk - 128) * 256 + tid;   // 0..16383
        const int b = tg >> 9;
        const int e = tg & 511;
        const float4* wr = (const float4*)(domW + (size_t)e * Dd);
        const float4* gr = (const float4*)(gf + (size_t)b * Dd);
        float acc = domb[e];
#pragma unroll 8
        for (int j = 0; j < Dd / 4; ++j) acc = dot4(gr[j], wr[j], acc);
        dom_ws[b * Dd + e] = acc;
    }
}

// ---------------- K5: prompt assembly (360 MB streaming write) ----------------
// Known: one block per (b, chunk of 10 c). dom[b]+sem[b] staged in LDS (18 KB, reused
// 10x); pre[c]/suf[c] from L2. All output stores nontemporal (never re-read; keep
// the 361 MB stream out of L2 so the token reads stay resident).
// grid = 1600 known + 32 unknown = 1632 blocks, 256 threads.
#define KN_CB 10
__global__ __launch_bounds__(256)
void k_assemble(const v4u* __restrict__ pre, const v4u* __restrict__ suf,
                const v4u* __restrict__ dom, const v4u* __restrict__ sem,
                const v4u* __restrict__ upre, const v4u* __restrict__ usuf,
                const v4u* __restrict__ ust,
                v4u* __restrict__ out0, v4u* __restrict__ out1) {
    __shared__ v4u s_tok[1152];   // [0,128): dom ; [128,1152): sem heads 0..7
    const int blk = blockIdx.x;
    const int tid = threadIdx.x;
    if (blk < Bb * (Cc / KN_CB)) {
        const int b = blk / (Cc / KN_CB);
        const int c0 = (blk % (Cc / KN_CB)) * KN_CB;
        for (int j = tid; j < 1152; j += 256)
            s_tok[j] = (j < 128) ? dom[b * 128 + j] : sem[b * 1024 + (j - 128)];
        __syncthreads();
#pragma unroll
        for (int cj = 0; cj < KN_CB; ++cj) {
            const int c = c0 + cj;
            v4u* row = out0 + (size_t)(b * Cc + c) * 1408;
#pragma unroll
            for (int k = 0; k < 6; ++k) {
                const int i = tid + k * 256;
                if (k < 5 || i < 1408) {
                    const int t = i >> 7;        // wave-uniform
                    const int off = i & 127;
                    v4u v;
                    if (t == 0) v = pre[c * 128 + off];
                    else if (t == 10) v = suf[c * 128 + off];
                    else v = s_tok[(t - 1) * 128 + off];   // t=1 dom, t=2..9 sem
                    __builtin_nontemporal_store(v, &row[i]);
                }
            }
        }
    } else {
        const int b = blk - Bb * (Cc / KN_CB);
#pragma unroll
        for (int k = 0; k < 4; ++k) {
            const int i = tid + k * 256;
            if (k < 3 || i < 896) {          // 7*512 fp32 = 896 v4u
                const int t = i >> 7;
                const int off = i & 127;
                v4u v;
                if (t == 0) v = upre[off];
                else if (t == 6) v = usuf[off];
                else if (t == 1) v = dom[b * 128 + off];
                else v = ust[(t - 2) * 128 + off];
                __builtin_nontemporal_store(v, &out1[b * 896 + i]);
            }
        }
    }
}

extern "C" void kernel_launch(void* const* d_in, const int* in_sizes, int n_in,
                              void* d_out, int out_size, void* d_ws, size_t ws_size,
                              hipStream_t stream) {
    const float* patch = (const float*)d_in[0];   // (B,P,D)
    const float* gf    = (const float*)d_in[1];   // (B,D)
    const float* query = (const float*)d_in[2];   // (H,D)
    const float* domW  = (const float*)d_in[3];   // (D,D)
    const float* domb  = (const float*)d_in[4];   // (D,)
    const float* semW  = (const float*)d_in[5];   // (H,D,D)
    const float* semb  = (const float*)d_in[6];   // (H,D)
    const float* ust   = (const float*)d_in[7];   // (U,D)
    const float* pre   = (const float*)d_in[8];   // (C,1,D)
    const float* suf   = (const float*)d_in[9];   // (C,1,D)
    const float* upre  = (const float*)d_in[10];  // (1,D)
    const float* usuf  = (const float*)d_in[11];  // (1,D)

    float* out = (float*)d_out;
    float* st_out = out + OUT2_ELEM_OFF;

    float* ws   = (float*)d_ws;
    float* sc_w = ws + WS_SC;
    float* part = ws + WS_PART;
    float* domp = ws + WS_DOM;
    float* semp = ws + WS_SEM;

    hipLaunchKernelGGL(k_scores, dim3(Bb * 49), dim3(256), 0, stream, patch, query, sc_w);
    hipLaunchKernelGGL(k_pool_part, dim3(Bb * NPC), dim3(256), 0, stream, patch, sc_w, part);
    hipLaunchKernelGGL(k_combine, dim3(128), dim3(256), 0, stream, part, st_out);
    hipLaunchKernelGGL(k_proj, dim3(192), dim3(256), 0, stream,
                       gf, domW, domb, semW, semb, st_out, domp, semp);
    hipLaunchKernelGGL(k_assemble, dim3(Bb * (Cc / KN_CB) + Bb), dim3(256), 0, stream,
                       (const v4u*)pre, (const v4u*)suf,
                       (const v4u*)domp, (const v4u*)semp,
                       (const v4u*)upre, (const v4u*)usuf, (const v4u*)ust,
                       (v4u*)out, (v4u*)(out + OUT1_ELEM_OFF));
}

// Round 2
// 434.305 us; speedup vs baseline: 1.0091x; 1.0091x over previous
//
#include <hip/hip_runtime.h>

typedef unsigned int uint32;
typedef uint32 v4u __attribute__((ext_vector_type(4)));

#define Bb 32
#define Pp 196
#define Dd 512
#define Hh 8
#define Uu 4
#define Cc 500

// Outputs (float32), concatenated flat:
// out0: known_prompts   (B*C, 11, D) -> 90,112,000 elems
// out1: unknown_prompts (B, 7, D)    -> 114,688 elems @ 90,112,000
// out2: semantic_tokens (B, H, D)    -> 131,072 elems @ 90,226,688
#define OUT1_ELEM_OFF 90112000
#define OUT2_ELEM_OFF 90226688

// v4u counts (out0 and out1 are contiguous -> one flat store stream)
#define OUT0_V4 22528000u          // 90,112,000 / 4
#define OUT1_V4 28672u             // 114,688 / 4
#define TOT_V4  (OUT0_V4 + OUT1_V4)

// ws layout (float element offsets; all 16B-aligned)
#define WS_SC   0          // scores (B,H,P)          = 50,176 floats
#define WS_DOM  51200      // projected_domain (B,D)  = 16,384 floats
#define WS_SEM  67584      // projected_sem (B,H,D)   = 131,072 floats

__device__ __forceinline__ float dot4(float4 a, float4 b, float acc) {
    acc = fmaf(a.x, b.x, acc);
    acc = fmaf(a.y, b.y, acc);
    acc = fmaf(a.z, b.z, acc);
    acc = fmaf(a.w, b.w, acc);
    return acc;
}

// ---------------- K1: scores[b,h,p] = patch[b,p,:].query[h,:] ----------------
// grid = B*49 = 1568, block = 256 (4 waves, one p per wave)
__global__ __launch_bounds__(256)
void k_scores(const float* __restrict__ patch, const float* __restrict__ query,
              float* __restrict__ sc) {
    __shared__ float s_q[Hh * Dd];   // 16 KB
    const int b = blockIdx.x / 49;
    const int p0 = (blockIdx.x % 49) * 4;
    const int tid = threadIdx.x;
    for (int j = tid; j < Hh * Dd / 4; j += 256)
        ((float4*)s_q)[j] = ((const float4*)query)[j];
    __syncthreads();

    const int wave = tid >> 6, lane = tid & 63;
    const int p = p0 + wave;
    const float* pr = patch + ((size_t)b * Pp + p) * Dd + lane * 8;
    const float4 v0 = *(const float4*)pr;
    const float4 v1 = *(const float4*)(pr + 4);

    float out = 0.f;
#pragma unroll
    for (int h = 0; h < 8; ++h) {
        const float4 q0 = *(const float4*)&s_q[h * Dd + lane * 8];
        const float4 q1 = *(const float4*)&s_q[h * Dd + lane * 8 + 4];
        float a = dot4(v0, q0, 0.f);
        a = dot4(v1, q1, a);
#pragma unroll
        for (int m = 32; m >= 1; m >>= 1) a += __shfl_xor(a, m, 64);
        if (lane == h) out = a;
    }
    if (lane < 8) sc[((size_t)b * Hh + lane) * Pp + p] = out;
}

// ---------------- K2: fused softmax + pooling -> semantic_tokens (out2) ----------------
// grid = B*4 = 128 (b, D-chunk of 128 floats), block = 256.
// Softmax recomputed per chunk (cheap); pooling accumulates sequentially over all
// 196 p — removes the (B,NPC,H,D) partials round-trip (17 MB) and k_combine.
__global__ __launch_bounds__(256)
void k_pool(const float* __restrict__ patch, const float* __restrict__ sc,
            float* __restrict__ st) {
    __shared__ float s_w[Hh * Pp];   // scores -> weights, 6.3 KB
    const int b = blockIdx.x >> 2;
    const int dc = blockIdx.x & 3;   // D-chunk: floats [dc*128, dc*128+128)
    const int tid = threadIdx.x;

    for (int j = tid; j < Hh * Pp; j += 256) s_w[j] = sc[(size_t)b * Hh * Pp + j];
    __syncthreads();

    // softmax over p for h = tid>>5, 32-lane group
    {
        const int h = tid >> 5, gl = tid & 31;
        float m = -1e30f;
        for (int p = gl; p < Pp; p += 32) m = fmaxf(m, s_w[h * Pp + p]);
#pragma unroll
        for (int mm = 16; mm >= 1; mm >>= 1) m = fmaxf(m, __shfl_xor(m, mm, 64));
        float s = 0.f;
        for (int p = gl; p < Pp; p += 32) s += __expf(s_w[h * Pp + p] - m);
#pragma unroll
        for (int mm = 16; mm >= 1; mm >>= 1) s += __shfl_xor(s, mm, 64);
        const float inv = 1.f / s;
        for (int p = gl; p < Pp; p += 32)
            s_w[h * Pp + p] = __expf(s_w[h * Pp + p] - m) * inv;  // disjoint p per thread
    }
    __syncthreads();

    // pool: thread = (h = tid>>5, f = tid&31 -> float4 within this D-chunk)
    const int h = tid >> 5;
    const int f = (tid & 31) + dc * 32;        // float4 index within D (0..127)
    const float4* pb4 = (const float4*)(patch + (size_t)b * Pp * Dd);
    float4 a = {0, 0, 0, 0};
#pragma unroll 4
    for (int p = 0; p < Pp; ++p) {
        const float w = s_w[h * Pp + p];
        const float4 pv = pb4[p * 128 + f];
        a.x = fmaf(w, pv.x, a.x);
        a.y = fmaf(w, pv.y, a.y);
        a.z = fmaf(w, pv.z, a.z);
        a.w = fmaf(w, pv.w, a.w);
    }
    ((float4*)st)[(size_t)b * 1024 + h * 128 + f] = a;
}

// ---------------- K3: dom + sem projections (LDS-tiled, vector ds_read) ----------------
// grid = 192: blk<128 -> sem (h = blk>>4, e-tile of 32); blk>=128 -> dom (64 blocks)
// PJS=516: rows 16B-aligned; thread reads rows {pe,pe+16}/{pb,pb+16} so ds_read_b128
// row-starts spread over all 8 bank-quads (<=2-way, free).
#define PJS 516
__global__ __launch_bounds__(256)
void k_proj(const float* __restrict__ gf, const float* __restrict__ domW,
            const float* __restrict__ domb, const float* __restrict__ semW,
            const float* __restrict__ semb, const float* __restrict__ st,
            float* __restrict__ dom_ws, float* __restrict__ sem_ws) {
    __shared__ float s_w[32 * PJS];    // 66,048 B
    __shared__ float s_st[32 * PJS];   // 66,048 B
    const int blk = blockIdx.x;
    const int tid = threadIdx.x;
    if (blk < 128) {
        const int h = blk >> 4;
        const int e0 = (blk & 15) * 32;
        for (int g = tid; g < 32 * 128; g += 256) {
            const int r = g >> 7, c4 = g & 127;
            const float4 w = ((const float4*)semW)[((size_t)(h * Dd + e0 + r)) * 128 + c4];
            *(float4*)&s_w[r * PJS + c4 * 4] = w;
            const float4 s = ((const float4*)st)[((size_t)(r * Hh + h)) * 128 + c4];
            *(float4*)&s_st[r * PJS + c4 * 4] = s;
        }
        __syncthreads();
        const int pe = tid & 15;       // e = e0 + pe, e0 + pe + 16
        const int pb = tid >> 4;       // b = pb, pb + 16
        const float* w0r = &s_w[pe * PJS];
        const float* w1r = &s_w[(pe + 16) * PJS];
        const float* s0r = &s_st[pb * PJS];
        const float* s1r = &s_st[(pb + 16) * PJS];
        float a00 = 0.f, a01 = 0.f, a10 = 0.f, a11 = 0.f;
#pragma unroll 4
        for (int d = 0; d < Dd; d += 4) {
            const float4 w0 = *(const float4*)&w0r[d];
            const float4 w1 = *(const float4*)&w1r[d];
            const float4 s0 = *(const float4*)&s0r[d];
            const float4 s1 = *(const float4*)&s1r[d];
            a00 = dot4(s0, w0, a00);
            a01 = dot4(s0, w1, a01);
            a10 = dot4(s1, w0, a10);
            a11 = dot4(s1, w1, a11);
        }
        const int e_ = e0 + pe;
        const float b0 = semb[h * Dd + e_], b1 = semb[h * Dd + e_ + 16];
        sem_ws[((size_t)pb * Hh + h) * Dd + e_]             = a00 + b0;
        sem_ws[((size_t)pb * Hh + h) * Dd + e_ + 16]        = a01 + b1;
        sem_ws[((size_t)(pb + 16) * Hh + h) * Dd + e_]      = a10 + b0;
        sem_ws[((size_t)(pb + 16) * Hh + h) * Dd + e_ + 16] = a11 + b1;
    } else {
        const int tg = (blk - 128) * 256 + tid;   // 0..16383
        const int b = tg >> 9;
        const int e = tg & 511;
        const float4* wr = (const float4*)(domW + (size_t)e * Dd);
        const float4* gr = (const float4*)(gf + (size_t)b * Dd);
        float acc = domb[e];
#pragma unroll 8
        for (int j = 0; j < Dd / 4; ++j) acc = dot4(gr[j], wr[j], acc);
        dom_ws[b * Dd + e] = acc;
    }
}

// ---------------- K4: prompt assembly — fill-clone store stream ----------------
// One flat grid-stride loop over out0||out1 (contiguous, 22,556,672 v4u = 361 MB).
// Mimics __amd_rocclr_fillBufferAligned (which hits 6.3 TB/s on this buffer):
// linear per-wave 1KB stores, plain (non-NT), 2048 blocks = 32 waves/CU.
// Source resolution per index via magic-constant division; 1408, 128, 896 are all
// divisible by 64 -> row/token/branch wave-uniform; source footprint 8.6 MB (L2).
__global__ __launch_bounds__(256)
void k_assemble(const v4u* __restrict__ pre, const v4u* __restrict__ suf,
                const v4u* __restrict__ dom, const v4u* __restrict__ sem,
                const v4u* __restrict__ upre, const v4u* __restrict__ usuf,
                const v4u* __restrict__ ust,
                v4u* __restrict__ outv) {
    const uint32 stride = gridDim.x * 256u;
    for (uint32 i = blockIdx.x * 256u + threadIdx.x; i < TOT_V4; i += stride) {
        v4u v;
        if (i < OUT0_V4) {
            const uint32 row = i / 1408u;            // magic-mul
            const uint32 rem = i - row * 1408u;
            const uint32 t = rem >> 7;               // token 0..10, wave-uniform
            const uint32 off = rem & 127u;
            const uint32 b = row / 500u;             // magic-mul
            const uint32 c = row - b * 500u;
            if (t == 0u)       v = pre[c * 128u + off];
            else if (t == 10u) v = suf[c * 128u + off];
            else if (t == 1u)  v = dom[b * 128u + off];
            else               v = sem[b * 1024u + (t - 2u) * 128u + off];
        } else {
            const uint32 j = i - OUT0_V4;
            const uint32 b = j / 896u;               // magic-mul
            const uint32 rem = j - b * 896u;
            const uint32 t = rem >> 7;
            const uint32 off = rem & 127u;
            if (t == 0u)      v = upre[off];
            else if (t == 6u) v = usuf[off];
            else if (t == 1u) v = dom[b * 128u + off];
            else              v = ust[(t - 2u) * 128u + off];
        }
        outv[i] = v;
    }
}

extern "C" void kernel_launch(void* const* d_in, const int* in_sizes, int n_in,
                              void* d_out, int out_size, void* d_ws, size_t ws_size,
                              hipStream_t stream) {
    const float* patch = (const float*)d_in[0];   // (B,P,D)
    const float* gf    = (const float*)d_in[1];   // (B,D)
    const float* query = (const float*)d_in[2];   // (H,D)
    const float* domW  = (const float*)d_in[3];   // (D,D)
    const float* domb  = (const float*)d_in[4];   // (D,)
    const float* semW  = (const float*)d_in[5];   // (H,D,D)
    const float* semb  = (const float*)d_in[6];   // (H,D)
    const float* ust   = (const float*)d_in[7];   // (U,D)
    const float* pre   = (const float*)d_in[8];   // (C,1,D)
    const float* suf   = (const float*)d_in[9];   // (C,1,D)
    const float* upre  = (const float*)d_in[10];  // (1,D)
    const float* usuf  = (const float*)d_in[11];  // (1,D)

    float* out = (float*)d_out;
    float* st_out = out + OUT2_ELEM_OFF;

    float* ws   = (float*)d_ws;
    float* sc_w = ws + WS_SC;
    float* domp = ws + WS_DOM;
    float* semp = ws + WS_SEM;

    hipLaunchKernelGGL(k_scores, dim3(Bb * 49), dim3(256), 0, stream, patch, query, sc_w);
    hipLaunchKernelGGL(k_pool, dim3(Bb * 4), dim3(256), 0, stream, patch, sc_w, st_out);
    hipLaunchKernelGGL(k_proj, dim3(192), dim3(256), 0, stream,
                       gf, domW, domb, semW, semb, st_out, domp, semp);
    hipLaunchKernelGGL(k_assemble, dim3(2048), dim3(256), 0, stream,
                       (const v4u*)pre, (const v4u*)suf,
                       (const v4u*)domp, (const v4u*)semp,
                       (const v4u*)upre, (const v4u*)usuf, (const v4u*)ust,
                       (v4u*)out);
}